// Round 3
// baseline (123.437 us; speedup 1.0000x reference)
//
#include <hip/hip_runtime.h>
#include <hip/hip_bf16.h>

typedef float  f32x4  __attribute__((ext_vector_type(4)));
typedef short  short8 __attribute__((ext_vector_type(8)));

#define KP   832   // padded K: 13 * 64
#define NKT  13
#define BM   64

static __device__ __forceinline__ unsigned short f2bf(float f) {
    unsigned int u = __float_as_uint(f);
    unsigned int r = (u + 0x7fffu + ((u >> 16) & 1u)) >> 16;   // RNE
    return (unsigned short)r;
}
static __device__ __forceinline__ float bf2f(unsigned short h) {
    return __uint_as_float(((unsigned int)h) << 16);
}

// Build W_eff = fc1_w o ConvMatrix : [128][KP] bf16 (zero-padded past 784)
__global__ __launch_bounds__(256) void weff_prep(
    const float* __restrict__ fc1_w,    // [128][676]
    const float* __restrict__ conv_w,   // [3][3]
    unsigned short* __restrict__ weff)  // [128][KP] bf16
{
    int idx = blockIdx.x * 256 + threadIdx.x;   // o*KP + p
    if (idx >= 128 * KP) return;
    int o = idx / KP, p = idx - o * KP;
    float s = 0.f;
    if (p < 784) {
        int y = p / 28, xx = p - y * 28;
        #pragma unroll
        for (int dr = 0; dr < 3; ++dr) {
            int r = y - dr;
            if (r < 0 || r > 25) continue;
            #pragma unroll
            for (int dc = 0; dc < 3; ++dc) {
                int c = xx - dc;
                if (c < 0 || c > 25) continue;
                s += fc1_w[o * 676 + r * 26 + c] * conv_w[dr * 3 + dc];
            }
        }
    }
    weff[idx] = f2bf(s);
}

// Fused: H = relu(X @ Weff^T + b1); out = H @ fc2^T + b2
// X staged fp32 via global_load_lds (fire-and-forget), double-buffered,
// XOR-swizzled via pre-swizzled global source. weff frags direct from L2.
// 8 waves: 4 row-waves x 2 col-waves; wave tile 16 rows x 64 cols.
__global__ __launch_bounds__(512, 4) void fused_fwd(
    const float* __restrict__ x,              // [B][784]
    const unsigned short* __restrict__ weff,  // [128][KP] bf16
    const float* __restrict__ fc1_b,          // [128]
    const float* __restrict__ fc2_w,          // [10][128]
    const float* __restrict__ fc2_b,          // [10]
    float* __restrict__ out,                  // [B][10]
    int B)
{
    __shared__ float As[2][4096];             // 2 x 64 rows x 64 f32 (16KB each)
    __shared__ unsigned short Hs[BM][136];    // 128 bf16 + 8 pad
    __shared__ float fc2w_s[1280];
    __shared__ float fc2b_s[16];

    const int tid  = threadIdx.x;
    const int lane = tid & 63;
    const int wid  = tid >> 6;                // 0..7
    const int wr   = wid >> 1;                // 0..3 (16-row band)
    const int wc   = wid & 1;                 // 0..1 (64-col half)
    const int r16  = lane & 15;
    const int kc   = lane >> 4;               // 0..3
    const int m0   = blockIdx.x * BM;

    for (int i = tid; i < 1280; i += 512) fc2w_s[i] = fc2_w[i];
    if (tid < 10) fc2b_s[tid] = fc2_b[tid];

    // ---- staging geometry (linear LDS dest, inverse-swizzled global src) ----
    // thread t covers LDS 16B-slot (row = q*32 + t/16, s16 = t%16) per round q.
    // read swizzle: slot' = (u&8) | ((u&7) ^ (row&7))  =>  source chunk
    // u = (s16&8) | ((s16&7) ^ (row&7)).
    const int st_row = wid * 4 + (lane >> 4);            // t>>4 (q adds 32, row&7 unchanged)
    const int st_s16 = lane & 15;
    const int st_u   = (st_s16 & 8) | ((st_s16 & 7) ^ (st_row & 7));

    auto stage = [&](int bufi, int kt) {
        int k = kt * 64 + st_u * 4;
        if (k + 4 > 784) k = 0;               // tail: finite filler, weff pad is 0
        const float* gp0 = x + (size_t)(m0 + st_row) * 784 + k;
        const float* gp1 = x + (size_t)(m0 + 32 + st_row) * 784 + k;
        auto* lp0 = (__attribute__((address_space(3))) float*)&As[bufi][wid * 256];
        auto* lp1 = (__attribute__((address_space(3))) float*)&As[bufi][2048 + wid * 256];
        __builtin_amdgcn_global_load_lds((const __attribute__((address_space(1))) void*)gp0,
                                         (__attribute__((address_space(3))) void*)lp0, 16, 0, 0);
        __builtin_amdgcn_global_load_lds((const __attribute__((address_space(1))) void*)gp1,
                                         (__attribute__((address_space(3))) void*)lp1, 16, 0, 0);
    };

    // B pointers: col-major rows of weff, k-offset kc*8 baked in
    const unsigned short* wp[4];
    #pragma unroll
    for (int j = 0; j < 4; ++j)
        wp[j] = weff + (size_t)(wc * 64 + j * 16 + r16) * KP + kc * 8;

    const int arow = wr * 16 + r16;           // A-fragment row in tile
    const int sw   = arow & 7;                // read-side XOR

    f32x4 acc[4];
    #pragma unroll
    for (int j = 0; j < 4; ++j) acc[j] = (f32x4)(0.f);

    int buf = 0;
    stage(0, 0);
    __syncthreads();                          // compiler drains vmcnt before barrier

    for (int kt = 0; kt < NKT; ++kt) {
        if (kt + 1 < NKT) stage(buf ^ 1, kt + 1);   // fire-and-forget next tile

        #pragma unroll
        for (int kk = 0; kk < 2; ++kk) {
            short8 bfv[4];
            #pragma unroll
            for (int j = 0; j < 4; ++j)
                bfv[j] = *reinterpret_cast<const short8*>(wp[j] + kt * 64 + kk * 32);

            const int s0 = kk * 8 + ((kc * 2 + 0) ^ sw);
            const int s1 = kk * 8 + ((kc * 2 + 1) ^ sw);
            f32x4 a0 = *reinterpret_cast<const f32x4*>(&As[buf][arow * 64 + s0 * 4]);
            f32x4 a1 = *reinterpret_cast<const f32x4*>(&As[buf][arow * 64 + s1 * 4]);

            __hip_bfloat162 p0 = __float22bfloat162_rn(make_float2(a0[0], a0[1]));
            __hip_bfloat162 p1 = __float22bfloat162_rn(make_float2(a0[2], a0[3]));
            __hip_bfloat162 p2 = __float22bfloat162_rn(make_float2(a1[0], a1[1]));
            __hip_bfloat162 p3 = __float22bfloat162_rn(make_float2(a1[2], a1[3]));
            short8 af;
            reinterpret_cast<unsigned int*>(&af)[0] = *reinterpret_cast<unsigned int*>(&p0);
            reinterpret_cast<unsigned int*>(&af)[1] = *reinterpret_cast<unsigned int*>(&p1);
            reinterpret_cast<unsigned int*>(&af)[2] = *reinterpret_cast<unsigned int*>(&p2);
            reinterpret_cast<unsigned int*>(&af)[3] = *reinterpret_cast<unsigned int*>(&p3);

            #pragma unroll
            for (int j = 0; j < 4; ++j)
                acc[j] = __builtin_amdgcn_mfma_f32_16x16x32_bf16(af, bfv[j], acc[j], 0, 0, 0);
        }
        __syncthreads();                      // next buffer staged + this buffer free
        buf ^= 1;
    }

    // ---- epilogue: bias + ReLU -> Hs (bf16); unique writer per cell
    #pragma unroll
    for (int j = 0; j < 4; ++j) {
        int ncol = wc * 64 + j * 16 + r16;
        float bias = fc1_b[ncol];
        #pragma unroll
        for (int r = 0; r < 4; ++r) {
            int mrow = wr * 16 + kc * 4 + r;
            float h = acc[j][r] + bias;
            Hs[mrow][ncol] = f2bf(h > 0.f ? h : 0.f);
        }
    }
    __syncthreads();

    // ---- stage 2: out[64][10] = Hs @ fc2^T + b2
    #pragma unroll
    for (int it = 0; it < 2; ++it) {
        int idx = it * 512 + tid;             // 0..1023, valid < 640
        if (idx < BM * 10) {
            int row = idx / 10, j = idx - row * 10;
            float sum = fc2b_s[j];
            const float* wrow = &fc2w_s[j * 128];
            #pragma unroll
            for (int n8 = 0; n8 < 16; ++n8) {
                short8 h = *reinterpret_cast<const short8*>(&Hs[row][n8 * 8]);
                #pragma unroll
                for (int k2 = 0; k2 < 8; ++k2)
                    sum += bf2f(((unsigned short*)&h)[k2]) * wrow[n8 * 8 + k2];
            }
            out[(size_t)(m0 + row) * 10 + j] = sum;
        }
    }
}

extern "C" void kernel_launch(void* const* d_in, const int* in_sizes, int n_in,
                              void* d_out, int out_size, void* d_ws, size_t ws_size,
                              hipStream_t stream) {
    const float* x      = (const float*)d_in[0];
    const float* conv_w = (const float*)d_in[1];
    const float* fc1_w  = (const float*)d_in[2];
    const float* fc1_b  = (const float*)d_in[3];
    const float* fc2_w  = (const float*)d_in[4];
    const float* fc2_b  = (const float*)d_in[5];
    float* out = (float*)d_out;
    unsigned short* weff = (unsigned short*)d_ws;   // 128*832*2 = 212992 B

    int B = in_sizes[0] / 784;

    weff_prep<<<(128 * KP + 255) / 256, 256, 0, stream>>>(fc1_w, conv_w, weff);

    int nblk = (B + BM - 1) / BM;
    fused_fwd<<<nblk, 512, 0, stream>>>(x, weff, fc1_b, fc2_w, fc2_b, out, B);
}

// Round 4
// 97.139 us; speedup vs baseline: 1.2707x; 1.2707x over previous
//
#include <hip/hip_runtime.h>
#include <hip/hip_bf16.h>

typedef float  f32x4  __attribute__((ext_vector_type(4)));
typedef short  short8 __attribute__((ext_vector_type(8)));

#define KP   800   // weff padded K (784 -> 25*32), zero-filled past 784
#define BM   64

static __device__ __forceinline__ unsigned short f2bf(float f) {
    unsigned int u = __float_as_uint(f);
    unsigned int r = (u + 0x7fffu + ((u >> 16) & 1u)) >> 16;   // RNE
    return (unsigned short)r;
}
static __device__ __forceinline__ float bf2f(unsigned short h) {
    return __uint_as_float(((unsigned int)h) << 16);
}

static __device__ __forceinline__ short8 cvt8(float4 a, float4 b) {
    __hip_bfloat162 p0 = __float22bfloat162_rn(make_float2(a.x, a.y));
    __hip_bfloat162 p1 = __float22bfloat162_rn(make_float2(a.z, a.w));
    __hip_bfloat162 p2 = __float22bfloat162_rn(make_float2(b.x, b.y));
    __hip_bfloat162 p3 = __float22bfloat162_rn(make_float2(b.z, b.w));
    short8 r;
    reinterpret_cast<unsigned int*>(&r)[0] = *reinterpret_cast<unsigned int*>(&p0);
    reinterpret_cast<unsigned int*>(&r)[1] = *reinterpret_cast<unsigned int*>(&p1);
    reinterpret_cast<unsigned int*>(&r)[2] = *reinterpret_cast<unsigned int*>(&p2);
    reinterpret_cast<unsigned int*>(&r)[3] = *reinterpret_cast<unsigned int*>(&p3);
    return r;
}

// Build W_eff = fc1_w o ConvMatrix : [128][KP] bf16 (zero-padded past 784)
__global__ __launch_bounds__(256) void weff_prep(
    const float* __restrict__ fc1_w,    // [128][676]
    const float* __restrict__ conv_w,   // [3][3]
    unsigned short* __restrict__ weff)  // [128][KP] bf16
{
    int idx = blockIdx.x * 256 + threadIdx.x;   // o*KP + p
    if (idx >= 128 * KP) return;
    int o = idx / KP, p = idx - o * KP;
    float s = 0.f;
    if (p < 784) {
        int y = p / 28, xx = p - y * 28;
        #pragma unroll
        for (int dr = 0; dr < 3; ++dr) {
            int r = y - dr;
            if (r < 0 || r > 25) continue;
            #pragma unroll
            for (int dc = 0; dc < 3; ++dc) {
                int c = xx - dc;
                if (c < 0 || c > 25) continue;
                s += fc1_w[o * 676 + r * 26 + c] * conv_w[dr * 3 + dc];
            }
        }
    }
    weff[idx] = f2bf(s);
}

// Fused: H = relu(X @ Weff^T + b1); out = H @ fc2^T + b2
// Barrier-free main loop. Each wave: 16 rows x 128 cols (8 MFMA/iter).
// X loads: branch-free, 1-deep register rotation (ca -> na) so the
// compiler keeps next-iter loads in flight across the MFMA chain.
// weff fragments direct from L1/L2 (shared by all 4 waves of the block).
__global__ __launch_bounds__(256, 4) void fused_fwd(
    const float* __restrict__ x,              // [B][784]
    const unsigned short* __restrict__ weff,  // [128][KP] bf16
    const float* __restrict__ fc1_b,          // [128]
    const float* __restrict__ fc2_w,          // [10][128]
    const float* __restrict__ fc2_b,          // [10]
    float* __restrict__ out,                  // [B][10]
    int B)
{
    __shared__ unsigned short Hs[BM][136];    // 128 bf16 + 8 pad
    __shared__ float fc2w_s[1280];
    __shared__ float fc2b_s[16];

    const int tid  = threadIdx.x;
    const int lane = tid & 63;
    const int wid  = tid >> 6;                // 0..3: 16-row band per wave
    const int r16  = lane & 15;
    const int kc   = lane >> 4;               // 0..3 (8-elem k-chunk)
    const int m0   = blockIdx.x * BM;

    for (int i = tid; i < 1280; i += 256) fc2w_s[i] = fc2_w[i];
    if (tid < 10) fc2b_s[tid] = fc2_b[tid];

    int row = m0 + wid * 16 + r16;
    if (row >= B) row = B - 1;
    const float4* xv = reinterpret_cast<const float4*>(x + (size_t)row * 784);
    // per-iter float4 index: kt*8 + kc*2

    const unsigned short* wp[8];
    #pragma unroll
    for (int j = 0; j < 8; ++j)
        wp[j] = weff + (size_t)(j * 16 + r16) * KP + kc * 8;

    f32x4 acc[8];
    #pragma unroll
    for (int j = 0; j < 8; ++j) acc[j] = (f32x4)(0.f);

    // prologue: iter-0 A loads
    float4 ca0 = xv[kc * 2];
    float4 ca1 = xv[kc * 2 + 1];

    #pragma unroll 4
    for (int kt = 0; kt < 24; ++kt) {
        // branch-free prefetch of next iter (kt==23: dummy re-read of k=0)
        const int nk = (kt + 1 < 24) ? (kt + 1) : 0;
        float4 na0 = xv[nk * 8 + kc * 2];
        float4 na1 = xv[nk * 8 + kc * 2 + 1];

        short8 af = cvt8(ca0, ca1);
        #pragma unroll
        for (int j = 0; j < 8; ++j) {
            short8 bfv = *reinterpret_cast<const short8*>(wp[j] + kt * 32);
            acc[j] = __builtin_amdgcn_mfma_f32_16x16x32_bf16(af, bfv, acc[j], 0, 0, 0);
        }
        ca0 = na0; ca1 = na1;
    }

    // tail: k = 768..799; x valid only to 783 (kc 0,1), weff pad is 0
    {
        float4 t0 = make_float4(0.f, 0.f, 0.f, 0.f), t1 = t0;
        if (kc < 2) { t0 = xv[24 * 8 + kc * 2]; t1 = xv[24 * 8 + kc * 2 + 1]; }
        short8 af = cvt8(t0, t1);
        #pragma unroll
        for (int j = 0; j < 8; ++j) {
            short8 bfv = *reinterpret_cast<const short8*>(wp[j] + 24 * 32);
            acc[j] = __builtin_amdgcn_mfma_f32_16x16x32_bf16(af, bfv, acc[j], 0, 0, 0);
        }
    }

    // ---- epilogue: bias + ReLU -> Hs (bf16); unique writer per cell
    #pragma unroll
    for (int j = 0; j < 8; ++j) {
        int ncol = j * 16 + r16;
        float bias = fc1_b[ncol];
        #pragma unroll
        for (int r = 0; r < 4; ++r) {
            int mrow = wid * 16 + kc * 4 + r;
            float h = acc[j][r] + bias;
            Hs[mrow][ncol] = f2bf(h > 0.f ? h : 0.f);
        }
    }
    __syncthreads();

    // ---- stage 2: out[64][10] = Hs @ fc2^T + b2
    #pragma unroll
    for (int it = 0; it < 3; ++it) {
        int idx = it * 256 + tid;             // 0..767, valid < 640
        if (idx < BM * 10) {
            int r = idx / 10, j = idx - r * 10;
            if ((m0 + r) < B) {
                float sum = fc2b_s[j];
                const float* wrow = &fc2w_s[j * 128];
                #pragma unroll
                for (int n8 = 0; n8 < 16; ++n8) {
                    short8 h = *reinterpret_cast<const short8*>(&Hs[r][n8 * 8]);
                    #pragma unroll
                    for (int k2 = 0; k2 < 8; ++k2)
                        sum += bf2f(((unsigned short*)&h)[k2]) * wrow[n8 * 8 + k2];
                }
                out[(size_t)(m0 + r) * 10 + j] = sum;
            }
        }
    }
}

extern "C" void kernel_launch(void* const* d_in, const int* in_sizes, int n_in,
                              void* d_out, int out_size, void* d_ws, size_t ws_size,
                              hipStream_t stream) {
    const float* x      = (const float*)d_in[0];
    const float* conv_w = (const float*)d_in[1];
    const float* fc1_w  = (const float*)d_in[2];
    const float* fc1_b  = (const float*)d_in[3];
    const float* fc2_w  = (const float*)d_in[4];
    const float* fc2_b  = (const float*)d_in[5];
    float* out = (float*)d_out;
    unsigned short* weff = (unsigned short*)d_ws;   // 128*800*2 = 204800 B

    int B = in_sizes[0] / 784;

    weff_prep<<<(128 * KP + 255) / 256, 256, 0, stream>>>(fc1_w, conv_w, weff);

    int nblk = (B + BM - 1) / BM;
    fused_fwd<<<nblk, 256, 0, stream>>>(x, weff, fc1_b, fc2_w, fc2_b, out, B);
}

// Round 5
// 81.613 us; speedup vs baseline: 1.5125x; 1.1902x over previous
//
#include <hip/hip_runtime.h>
#include <hip/hip_bf16.h>

typedef float  f32x4  __attribute__((ext_vector_type(4)));
typedef short  short8 __attribute__((ext_vector_type(8)));

#define KP   800   // weff padded K (784 -> 25*32), zero-filled past 784
#define BM   64

static __device__ __forceinline__ unsigned short f2bf(float f) {
    unsigned int u = __float_as_uint(f);
    unsigned int r = (u + 0x7fffu + ((u >> 16) & 1u)) >> 16;   // RNE
    return (unsigned short)r;
}
static __device__ __forceinline__ float bf2f(unsigned short h) {
    return __uint_as_float(((unsigned int)h) << 16);
}

static __device__ __forceinline__ short8 cvt8(float4 a, float4 b) {
    __hip_bfloat162 p0 = __float22bfloat162_rn(make_float2(a.x, a.y));
    __hip_bfloat162 p1 = __float22bfloat162_rn(make_float2(a.z, a.w));
    __hip_bfloat162 p2 = __float22bfloat162_rn(make_float2(b.x, b.y));
    __hip_bfloat162 p3 = __float22bfloat162_rn(make_float2(b.z, b.w));
    short8 r;
    reinterpret_cast<unsigned int*>(&r)[0] = *reinterpret_cast<unsigned int*>(&p0);
    reinterpret_cast<unsigned int*>(&r)[1] = *reinterpret_cast<unsigned int*>(&p1);
    reinterpret_cast<unsigned int*>(&r)[2] = *reinterpret_cast<unsigned int*>(&p2);
    reinterpret_cast<unsigned int*>(&r)[3] = *reinterpret_cast<unsigned int*>(&p3);
    return r;
}

// Build W_eff = fc1_w o ConvMatrix, stored K-MAJOR: weff2[(p/8)][o][p%8]
// i.e. element index = (p>>3)*1024 + o*8 + (p&7). Zero-padded past p=783.
__global__ __launch_bounds__(256) void weff_prep(
    const float* __restrict__ fc1_w,    // [128][676]
    const float* __restrict__ conv_w,   // [3][3]
    unsigned short* __restrict__ weff2) // [KP/8][128][8] bf16
{
    int idx = blockIdx.x * 256 + threadIdx.x;   // o*KP + p
    if (idx >= 128 * KP) return;
    int o = idx / KP, p = idx - o * KP;
    float s = 0.f;
    if (p < 784) {
        int y = p / 28, xx = p - y * 28;
        #pragma unroll
        for (int dr = 0; dr < 3; ++dr) {
            int r = y - dr;
            if (r < 0 || r > 25) continue;
            #pragma unroll
            for (int dc = 0; dc < 3; ++dc) {
                int c = xx - dc;
                if (c < 0 || c > 25) continue;
                s += fc1_w[o * 676 + r * 26 + c] * conv_w[dr * 3 + dc];
            }
        }
    }
    weff2[(p >> 3) * 1024 + o * 8 + (p & 7)] = f2bf(s);
}

// Fused: H = relu(X @ Weff^T + b1); out = H @ fc2^T + b2
// 8 waves (4 row x 2 col), wave tile 16 rows x 64 cols, acc = 16 VGPR.
// Barrier-free main loop; branch-free 1-deep A rotation; B direct from
// L1/L2 with uniform-base + imm addressing (k-major weff layout).
// Grid 1024 x 512 thr -> 4 blocks/CU x 8 waves = 32 waves/CU (TLP lever).
__global__ __launch_bounds__(512, 8) void fused_fwd(
    const float* __restrict__ x,              // [B][784]
    const unsigned short* __restrict__ weff2, // [KP/8][128][8] bf16
    const float* __restrict__ fc1_b,          // [128]
    const float* __restrict__ fc2_w,          // [10][128]
    const float* __restrict__ fc2_b,          // [10]
    float* __restrict__ out,                  // [B][10]
    int B)
{
    __shared__ unsigned short Hs[BM][136];    // 128 bf16 + 8 pad
    __shared__ float fc2w_s[1280];
    __shared__ float fc2b_s[16];

    const int tid  = threadIdx.x;
    const int lane = tid & 63;
    const int wid  = tid >> 6;                // 0..7
    const int wr   = wid >> 1;                // 0..3: 16-row band
    const int wc   = wid & 1;                 // 0..1: 64-col half
    const int r16  = lane & 15;
    const int kc   = lane >> 4;               // 0..3 (8-elem k-chunk)
    const int m0   = blockIdx.x * BM;

    for (int i = tid; i < 1280; i += 512) fc2w_s[i] = fc2_w[i];
    if (tid < 10) fc2b_s[tid] = fc2_b[tid];

    int row = m0 + wr * 16 + r16;
    if (row >= B) row = B - 1;
    const float4* xv = reinterpret_cast<const float4*>(x + (size_t)row * 784);
    // A float4 index per iter: kt*8 + kc*2  (byte offsets fold to imm)

    // B: uniform kt stride 4096 elems; per-lane offset kc*1024 + (wc*64+r16)*8;
    // j in 0..3 adds 128 elems (256B imm).
    const unsigned short* wb = weff2 + kc * 1024 + (size_t)(wc * 64 + r16) * 8;

    f32x4 acc[4];
    #pragma unroll
    for (int j = 0; j < 4; ++j) acc[j] = (f32x4)(0.f);

    float4 ca0 = xv[kc * 2];
    float4 ca1 = xv[kc * 2 + 1];

    #pragma unroll 4
    for (int kt = 0; kt < 24; ++kt) {
        const int nk = (kt + 1 < 24) ? (kt + 1) : 0;   // branch-free dummy on last
        float4 na0 = xv[nk * 8 + kc * 2];
        float4 na1 = xv[nk * 8 + kc * 2 + 1];

        short8 af = cvt8(ca0, ca1);
        const unsigned short* wt = wb + kt * 4096;
        #pragma unroll
        for (int j = 0; j < 4; ++j) {
            short8 bfv = *reinterpret_cast<const short8*>(wt + j * 128);
            acc[j] = __builtin_amdgcn_mfma_f32_16x16x32_bf16(af, bfv, acc[j], 0, 0, 0);
        }
        ca0 = na0; ca1 = na1;
    }

    // tail: kt=24 covers k=768..799; x valid only for kc<2; weff pad is 0
    {
        float4 t0 = make_float4(0.f, 0.f, 0.f, 0.f), t1 = t0;
        if (kc < 2) { t0 = xv[24 * 8 + kc * 2]; t1 = xv[24 * 8 + kc * 2 + 1]; }
        short8 af = cvt8(t0, t1);
        const unsigned short* wt = wb + 24 * 4096;
        #pragma unroll
        for (int j = 0; j < 4; ++j) {
            short8 bfv = *reinterpret_cast<const short8*>(wt + j * 128);
            acc[j] = __builtin_amdgcn_mfma_f32_16x16x32_bf16(af, bfv, acc[j], 0, 0, 0);
        }
    }

    // ---- epilogue: bias + ReLU -> Hs (bf16); unique writer per cell
    #pragma unroll
    for (int j = 0; j < 4; ++j) {
        int ncol = wc * 64 + j * 16 + r16;
        float bias = fc1_b[ncol];
        #pragma unroll
        for (int r = 0; r < 4; ++r) {
            int mrow = wr * 16 + kc * 4 + r;
            float h = acc[j][r] + bias;
            Hs[mrow][ncol] = f2bf(h > 0.f ? h : 0.f);
        }
    }
    __syncthreads();

    // ---- stage 2: out[64][10] = Hs @ fc2^T + b2
    #pragma unroll
    for (int it = 0; it < 2; ++it) {
        int idx = it * 512 + tid;             // 0..1023, valid < 640
        if (idx < BM * 10) {
            int r = idx / 10, j = idx - r * 10;
            if ((m0 + r) < B) {
                float sum = fc2b_s[j];
                const float* wrow = &fc2w_s[j * 128];
                #pragma unroll
                for (int n8 = 0; n8 < 16; ++n8) {
                    short8 h = *reinterpret_cast<const short8*>(&Hs[r][n8 * 8]);
                    #pragma unroll
                    for (int k2 = 0; k2 < 8; ++k2)
                        sum += bf2f(((unsigned short*)&h)[k2]) * wrow[n8 * 8 + k2];
                }
                out[(size_t)(m0 + r) * 10 + j] = sum;
            }
        }
    }
}

extern "C" void kernel_launch(void* const* d_in, const int* in_sizes, int n_in,
                              void* d_out, int out_size, void* d_ws, size_t ws_size,
                              hipStream_t stream) {
    const float* x      = (const float*)d_in[0];
    const float* conv_w = (const float*)d_in[1];
    const float* fc1_w  = (const float*)d_in[2];
    const float* fc1_b  = (const float*)d_in[3];
    const float* fc2_w  = (const float*)d_in[4];
    const float* fc2_b  = (const float*)d_in[5];
    float* out = (float*)d_out;
    unsigned short* weff2 = (unsigned short*)d_ws;   // 100*1024*2 = 204800 B

    int B = in_sizes[0] / 784;

    weff_prep<<<(128 * KP + 255) / 256, 256, 0, stream>>>(fc1_w, conv_w, weff2);

    int nblk = (B + BM - 1) / BM;
    fused_fwd<<<nblk, 512, 0, stream>>>(x, weff2, fc1_b, fc2_w, fc2_b, out, B);
}

// Round 6
// 60.537 us; speedup vs baseline: 2.0391x; 1.3482x over previous
//
#include <hip/hip_runtime.h>
#include <hip/hip_bf16.h>

typedef float  f32x4  __attribute__((ext_vector_type(4)));
typedef short  short8 __attribute__((ext_vector_type(8)));

#define NKT    25            // K-steps of 32 (784 -> 800 padded)
#define BM     128
#define ABYTES 16384         // A stage: 128 rows x 32 f32
#define BBYTES 8192          // B stage: 128 cols x 32 bf16
#define SBYTES (ABYTES + BBYTES)

static __device__ __forceinline__ unsigned short f2bf(float f) {
    unsigned int u = __float_as_uint(f);
    unsigned int r = (u + 0x7fffu + ((u >> 16) & 1u)) >> 16;   // RNE
    return (unsigned short)r;
}
static __device__ __forceinline__ float bf2f(unsigned short h) {
    return __uint_as_float(((unsigned int)h) << 16);
}
static __device__ __forceinline__ short8 cvt8(f32x4 a, f32x4 b) {
    __hip_bfloat162 p0 = __float22bfloat162_rn(make_float2(a[0], a[1]));
    __hip_bfloat162 p1 = __float22bfloat162_rn(make_float2(a[2], a[3]));
    __hip_bfloat162 p2 = __float22bfloat162_rn(make_float2(b[0], b[1]));
    __hip_bfloat162 p3 = __float22bfloat162_rn(make_float2(b[2], b[3]));
    short8 r;
    reinterpret_cast<unsigned int*>(&r)[0] = *reinterpret_cast<unsigned int*>(&p0);
    reinterpret_cast<unsigned int*>(&r)[1] = *reinterpret_cast<unsigned int*>(&p1);
    reinterpret_cast<unsigned int*>(&r)[2] = *reinterpret_cast<unsigned int*>(&p2);
    reinterpret_cast<unsigned int*>(&r)[3] = *reinterpret_cast<unsigned int*>(&p3);
    return r;
}

// W_eff = fc1_w o ConvMatrix, K-MAJOR tiles: weff3[kt][col][32] bf16,
// element index = kt*4096 + o*32 + kk  (p = kt*32+kk). Zero past p=783.
__global__ __launch_bounds__(256) void weff_prep(
    const float* __restrict__ fc1_w,    // [128][676]
    const float* __restrict__ conv_w,   // [3][3]
    unsigned short* __restrict__ weff3) // [25][128][32] bf16
{
    int idx = blockIdx.x * 256 + threadIdx.x;   // o*800 + p
    if (idx >= 128 * 800) return;
    int o = idx / 800, p = idx - o * 800;
    float s = 0.f;
    if (p < 784) {
        int y = p / 28, xx = p - y * 28;
        #pragma unroll
        for (int dr = 0; dr < 3; ++dr) {
            int r = y - dr;
            if (r < 0 || r > 25) continue;
            #pragma unroll
            for (int dc = 0; dc < 3; ++dc) {
                int c = xx - dc;
                if (c < 0 || c > 25) continue;
                s += fc1_w[o * 676 + r * 26 + c] * conv_w[dr * 3 + dc];
            }
        }
    }
    weff3[(p >> 5) * 4096 + o * 32 + (p & 31)] = f2bf(s);
}

// Fused: H = relu(X @ Weff^T + b1); out = H @ fc2^T + b2
// T3+T4: 3-deep global_load_lds pipeline, counted vmcnt (never 0 in
// steady state), raw s_barrier. A fp32 + B bf16 staged coalesced; LDS
// reads conflict-free via source-side XOR swizzle (rule 21).
__global__ __launch_bounds__(512, 4) void fused_fwd(
    const float* __restrict__ x,              // [B][784]
    const unsigned short* __restrict__ weff3, // [25][128][32] bf16
    const float* __restrict__ fc1_b,          // [128]
    const float* __restrict__ fc2_w,          // [10][128]
    const float* __restrict__ fc2_b,          // [10]
    float* __restrict__ out,                  // [B][10]
    int B)
{
    __shared__ __align__(16) char pool[3 * SBYTES];   // 72 KB; Hs overlays later
    __shared__ float fc2w_s[1280];
    __shared__ float fc2b_s[16];

    const int tid  = threadIdx.x;
    const int lane = tid & 63;
    const int wid  = tid >> 6;                // 0..7
    const int wr   = wid >> 1;                // 0..3: 32-row band
    const int wc   = wid & 1;                 // 0..1: 64-col half
    const int r16  = lane & 15;
    const int kc   = lane >> 4;               // 0..3
    const int m0   = blockIdx.x * BM;

    // fc2 preload first, then drain so vmcnt counting below is exact
    for (int i = tid; i < 1280; i += 512) fc2w_s[i] = fc2_w[i];
    if (tid < 10) fc2b_s[tid] = fc2_b[tid];
    asm volatile("s_waitcnt vmcnt(0)" ::: "memory");

    // ---- staging constants (per thread) ----
    // A: 2 instrs; instr q covers LDS 16B-slot S = wid*128 + q*64 + lane
    //    slot (row, c) holds global chunk u = c ^ (row&7) of that row.
    const int aS0 = wid * 128 + lane;
    const int aS1 = aS0 + 64;
    const int arow0 = aS0 >> 3, au0 = ((aS0 & 7) ^ (arow0 & 7)) * 4;
    const int arow1 = aS1 >> 3, au1 = ((aS1 & 7) ^ (arow1 & 7)) * 4;
    int gr0 = m0 + arow0; if (gr0 >= B) gr0 = B - 1;
    int gr1 = m0 + arow1; if (gr1 >= B) gr1 = B - 1;
    const float* xr0 = x + (size_t)gr0 * 784;
    const float* xr1 = x + (size_t)gr1 * 784;
    // B: 1 instr; slot S = tid -> (col = tid>>2, c = tid&3); holds chunk
    //    u = c ^ ((col>>1)&3).
    const int bcol = tid >> 2, bcc = tid & 3;
    const int boff = bcol * 32 + (bcc ^ ((bcol >> 1) & 3)) * 8;   // elems

#define STAGE(bo_, kt_) do {                                                    \
        int k0_ = (kt_) * 32 + au0; if (k0_ > 780) k0_ = 0;                     \
        int k1_ = (kt_) * 32 + au1; if (k1_ > 780) k1_ = 0;                     \
        const float* g0_ = xr0 + k0_;                                           \
        const float* g1_ = xr1 + k1_;                                           \
        const unsigned short* g2_ = weff3 + (kt_) * 4096 + boff;                \
        char* la_ = pool + (bo_) + wid * 2048;                                  \
        char* lb_ = pool + (bo_) + ABYTES + wid * 1024;                         \
        __builtin_amdgcn_global_load_lds(                                       \
            (const __attribute__((address_space(1))) void*)g0_,                 \
            (__attribute__((address_space(3))) void*)la_, 16, 0, 0);            \
        __builtin_amdgcn_global_load_lds(                                       \
            (const __attribute__((address_space(1))) void*)g1_,                 \
            (__attribute__((address_space(3))) void*)(la_ + 1024), 16, 0, 0);   \
        __builtin_amdgcn_global_load_lds(                                       \
            (const __attribute__((address_space(1))) void*)g2_,                 \
            (__attribute__((address_space(3))) void*)lb_, 16, 0, 0);            \
    } while (0)

    // ---- read-side constants ----
    const int rowA0 = wr * 32 + r16;
    const int rowA1 = rowA0 + 16;
    const int offA00 = rowA0 * 128 + (((kc * 2)    ) ^ (rowA0 & 7)) * 16;
    const int offA01 = rowA0 * 128 + (((kc * 2) | 1) ^ (rowA0 & 7)) * 16;
    const int offA10 = rowA1 * 128 + (((kc * 2)    ) ^ (rowA1 & 7)) * 16;
    const int offA11 = rowA1 * 128 + (((kc * 2) | 1) ^ (rowA1 & 7)) * 16;
    int offB[4];
    #pragma unroll
    for (int j = 0; j < 4; ++j) {
        int col = wc * 64 + j * 16 + r16;
        offB[j] = ABYTES + col * 64 + (kc ^ ((col >> 1) & 3)) * 16;
    }

    f32x4 acc[2][4];
    #pragma unroll
    for (int m = 0; m < 2; ++m)
        #pragma unroll
        for (int j = 0; j < 4; ++j) acc[m][j] = (f32x4)(0.f);

    // ---- prologue: fill 3 stages ----
    STAGE(0, 0);
    STAGE(SBYTES, 1);
    STAGE(2 * SBYTES, 2);

    int bo = 0;
    for (int i = 0; i < NKT; ++i) {
        if (i < NKT - 2)       asm volatile("s_waitcnt vmcnt(6)" ::: "memory");
        else if (i == NKT - 2) asm volatile("s_waitcnt vmcnt(3)" ::: "memory");
        else                   asm volatile("s_waitcnt vmcnt(0)" ::: "memory");
        __builtin_amdgcn_s_barrier();          // stage i visible to all waves

        const char* bs = pool + bo;
        f32x4 a00 = *reinterpret_cast<const f32x4*>(bs + offA00);
        f32x4 a01 = *reinterpret_cast<const f32x4*>(bs + offA01);
        f32x4 a10 = *reinterpret_cast<const f32x4*>(bs + offA10);
        f32x4 a11 = *reinterpret_cast<const f32x4*>(bs + offA11);
        short8 b0 = *reinterpret_cast<const short8*>(bs + offB[0]);
        short8 b1 = *reinterpret_cast<const short8*>(bs + offB[1]);
        short8 b2 = *reinterpret_cast<const short8*>(bs + offB[2]);
        short8 b3 = *reinterpret_cast<const short8*>(bs + offB[3]);

        asm volatile("s_waitcnt lgkmcnt(0)" ::: "memory");
        __builtin_amdgcn_sched_barrier(0);
        __builtin_amdgcn_s_barrier();          // all reads of this buffer done
        __builtin_amdgcn_sched_barrier(0);

        if (i + 3 < NKT) STAGE(bo, i + 3);     // refill same buffer, 3 ahead

        short8 af0 = cvt8(a00, a01);
        short8 af1 = cvt8(a10, a11);
        acc[0][0] = __builtin_amdgcn_mfma_f32_16x16x32_bf16(af0, b0, acc[0][0], 0, 0, 0);
        acc[0][1] = __builtin_amdgcn_mfma_f32_16x16x32_bf16(af0, b1, acc[0][1], 0, 0, 0);
        acc[0][2] = __builtin_amdgcn_mfma_f32_16x16x32_bf16(af0, b2, acc[0][2], 0, 0, 0);
        acc[0][3] = __builtin_amdgcn_mfma_f32_16x16x32_bf16(af0, b3, acc[0][3], 0, 0, 0);
        acc[1][0] = __builtin_amdgcn_mfma_f32_16x16x32_bf16(af1, b0, acc[1][0], 0, 0, 0);
        acc[1][1] = __builtin_amdgcn_mfma_f32_16x16x32_bf16(af1, b1, acc[1][1], 0, 0, 0);
        acc[1][2] = __builtin_amdgcn_mfma_f32_16x16x32_bf16(af1, b2, acc[1][2], 0, 0, 0);
        acc[1][3] = __builtin_amdgcn_mfma_f32_16x16x32_bf16(af1, b3, acc[1][3], 0, 0, 0);

        bo += SBYTES;
        if (bo == 3 * SBYTES) bo = 0;
    }
#undef STAGE

    // ---- epilogue: bias + ReLU -> Hs (overlays staging pool) ----
    unsigned short (*Hs)[136] = (unsigned short (*)[136])pool;
    #pragma unroll
    for (int m = 0; m < 2; ++m) {
        #pragma unroll
        for (int j = 0; j < 4; ++j) {
            int ncol = wc * 64 + j * 16 + r16;
            float bias = fc1_b[ncol];
            #pragma unroll
            for (int r = 0; r < 4; ++r) {
                int mrow = wr * 32 + m * 16 + kc * 4 + r;
                float h = acc[m][j][r] + bias;
                Hs[mrow][ncol] = f2bf(h > 0.f ? h : 0.f);
            }
        }
    }
    __syncthreads();

    // ---- stage 2: out[128][10] = Hs @ fc2^T + b2 ----
    #pragma unroll
    for (int it = 0; it < 3; ++it) {
        int idx = it * 512 + tid;              // 0..1535, valid < 1280
        if (idx < BM * 10) {
            int row = idx / 10, j = idx - row * 10;
            if ((m0 + row) < B) {
                float sum = fc2b_s[j];
                const float* wrow = &fc2w_s[j * 128];
                #pragma unroll
                for (int n8 = 0; n8 < 16; ++n8) {
                    short8 h = *reinterpret_cast<const short8*>(&Hs[row][n8 * 8]);
                    #pragma unroll
                    for (int k2 = 0; k2 < 8; ++k2)
                        sum += bf2f(((unsigned short*)&h)[k2]) * wrow[n8 * 8 + k2];
                }
                out[(size_t)(m0 + row) * 10 + j] = sum;
            }
        }
    }
}

extern "C" void kernel_launch(void* const* d_in, const int* in_sizes, int n_in,
                              void* d_out, int out_size, void* d_ws, size_t ws_size,
                              hipStream_t stream) {
    const float* x      = (const float*)d_in[0];
    const float* conv_w = (const float*)d_in[1];
    const float* fc1_w  = (const float*)d_in[2];
    const float* fc1_b  = (const float*)d_in[3];
    const float* fc2_w  = (const float*)d_in[4];
    const float* fc2_b  = (const float*)d_in[5];
    float* out = (float*)d_out;
    unsigned short* weff3 = (unsigned short*)d_ws;   // 25*4096*2 = 204800 B

    int B = in_sizes[0] / 784;

    weff_prep<<<(128 * 800 + 255) / 256, 256, 0, stream>>>(fc1_w, conv_w, weff3);

    int nblk = (B + BM - 1) / BM;
    fused_fwd<<<nblk, 512, 0, stream>>>(x, weff3, fc1_b, fc2_w, fc2_b, out, B);
}